// Round 1
// baseline (1064.460 us; speedup 1.0000x reference)
//
#include <hip/hip_runtime.h>

#define TT 1024
#define SSZ 1024
#define DD 64
#define BHN 64
#define BSZN 4
#define EEN 1024
#define EPSF 1e-6f

// scratch for the gathered attention matrix [T, BSZ, E] = 16 MB (static to avoid ws_size assumptions)
__device__ float g_X[(size_t)TT * BSZN * EEN];

// ---------------- DPP wave-scan helpers (canonical gfx9 64-lane scan) ----------------
template<int CTRL, int RM>
__device__ __forceinline__ float f_dpp(float x, float ident) {
  return __builtin_bit_cast(float,
      __builtin_amdgcn_update_dpp(__builtin_bit_cast(int, ident),
                                  __builtin_bit_cast(int, x),
                                  CTRL, RM, 0xF, false));
}

__device__ __forceinline__ float wscan_mul(float x) {
  x *= f_dpp<0x111, 0xF>(x, 1.0f);   // row_shr:1
  x *= f_dpp<0x112, 0xF>(x, 1.0f);   // row_shr:2
  x *= f_dpp<0x114, 0xF>(x, 1.0f);   // row_shr:4
  x *= f_dpp<0x118, 0xF>(x, 1.0f);   // row_shr:8
  x *= f_dpp<0x142, 0xA>(x, 1.0f);   // row_bcast:15 rows 1,3
  x *= f_dpp<0x143, 0xC>(x, 1.0f);   // row_bcast:31 rows 2,3
  return x;
}

__device__ __forceinline__ float wscan_add(float x) {
  x += f_dpp<0x111, 0xF>(x, 0.0f);
  x += f_dpp<0x112, 0xF>(x, 0.0f);
  x += f_dpp<0x114, 0xF>(x, 0.0f);
  x += f_dpp<0x118, 0xF>(x, 0.0f);
  x += f_dpp<0x142, 0xA>(x, 0.0f);
  x += f_dpp<0x143, 0xC>(x, 0.0f);
  return x;
}

__device__ __forceinline__ float wave_shr1(float x, float ident) {
  return f_dpp<0x138, 0xF>(x, ident);  // wave_shr:1 (lane0 -> ident)
}

// ---------------- K1: p_choose = sigmoid(Q K^T + bias) -> alpha region ----------------
__global__ __launch_bounds__(256) void k_energy(const float* __restrict__ Q,
                                                const float* __restrict__ Kp,
                                                const float* __restrict__ eb,
                                                float* __restrict__ P) {
  __shared__ float As[64][132];  // [k][m], transposed
  __shared__ float Bs[64][132];  // [k][n], transposed
  const int tid = threadIdx.x;
  const int b = blockIdx.x >> 6;
  const int tile = blockIdx.x & 63;
  const int m0 = (tile >> 3) << 7;
  const int n0 = (tile & 7) << 7;

  {
    const int kc = (tid & 15) << 2;       // k block of 4
    const int rr = (tid >> 4) << 2;       // row block of 4 (covers 64/pass)
    const float* qb = Q + (size_t)b * TT * DD;
    const float* kb = Kp + (size_t)b * SSZ * DD;
#pragma unroll
    for (int pass = 0; pass < 2; ++pass) {
      const int r = rr + (pass << 6);
      float4 a0 = *(const float4*)(qb + (size_t)(m0 + r + 0) * DD + kc);
      float4 a1 = *(const float4*)(qb + (size_t)(m0 + r + 1) * DD + kc);
      float4 a2 = *(const float4*)(qb + (size_t)(m0 + r + 2) * DD + kc);
      float4 a3 = *(const float4*)(qb + (size_t)(m0 + r + 3) * DD + kc);
      *(float4*)&As[kc + 0][r] = make_float4(a0.x, a1.x, a2.x, a3.x);
      *(float4*)&As[kc + 1][r] = make_float4(a0.y, a1.y, a2.y, a3.y);
      *(float4*)&As[kc + 2][r] = make_float4(a0.z, a1.z, a2.z, a3.z);
      *(float4*)&As[kc + 3][r] = make_float4(a0.w, a1.w, a2.w, a3.w);
      float4 b0 = *(const float4*)(kb + (size_t)(n0 + r + 0) * DD + kc);
      float4 b1 = *(const float4*)(kb + (size_t)(n0 + r + 1) * DD + kc);
      float4 b2 = *(const float4*)(kb + (size_t)(n0 + r + 2) * DD + kc);
      float4 b3 = *(const float4*)(kb + (size_t)(n0 + r + 3) * DD + kc);
      *(float4*)&Bs[kc + 0][r] = make_float4(b0.x, b1.x, b2.x, b3.x);
      *(float4*)&Bs[kc + 1][r] = make_float4(b0.y, b1.y, b2.y, b3.y);
      *(float4*)&Bs[kc + 2][r] = make_float4(b0.z, b1.z, b2.z, b3.z);
      *(float4*)&Bs[kc + 3][r] = make_float4(b0.w, b1.w, b2.w, b3.w);
    }
  }
  __syncthreads();

  const int tx = tid & 15, ty = tid >> 4;
  float acc[8][8];
#pragma unroll
  for (int i = 0; i < 8; ++i)
#pragma unroll
    for (int j = 0; j < 8; ++j) acc[i][j] = 0.0f;

#pragma unroll 8
  for (int k = 0; k < 64; ++k) {
    float4 a0 = *(const float4*)&As[k][ty << 3];
    float4 a1 = *(const float4*)&As[k][(ty << 3) + 4];
    float4 b0 = *(const float4*)&Bs[k][tx << 3];
    float4 b1 = *(const float4*)&Bs[k][(tx << 3) + 4];
    float av[8] = {a0.x, a0.y, a0.z, a0.w, a1.x, a1.y, a1.z, a1.w};
    float bv[8] = {b0.x, b0.y, b0.z, b0.w, b1.x, b1.y, b1.z, b1.w};
#pragma unroll
    for (int i = 0; i < 8; ++i)
#pragma unroll
      for (int j = 0; j < 8; ++j) acc[i][j] = fmaf(av[i], bv[j], acc[i][j]);
  }

  const float bias = eb[0];
#pragma unroll
  for (int i = 0; i < 8; ++i) {
    const size_t row = (size_t)b * TT + m0 + (ty << 3) + i;
    float o[8];
#pragma unroll
    for (int j = 0; j < 8; ++j) {
      float x = acc[i][j] + bias;
      o[j] = __builtin_amdgcn_rcpf(1.0f + __expf(-x));  // sigmoid
    }
    float* dst = P + row * SSZ + n0 + (tx << 3);
    *(float4*)dst = make_float4(o[0], o[1], o[2], o[3]);
    *(float4*)(dst + 4) = make_float4(o[4], o[5], o[6], o[7]);
  }
}

// ---------------- K2: sequential expected-alignment scan (in-place p -> alpha) ----------------
__device__ __forceinline__ void scan_step(float (&prev)[16], float (&buf)[16],
                                          float* base, int t, int lane) {
  // f = clamp(1 - p, EPS, 1)  (consumes buf so we can prefetch into it)
  float f[16];
#pragma unroll
  for (int i = 0; i < 16; ++i) {
    float om = 1.0f - buf[i];
    f[i] = fminf(fmaxf(om, EPSF), 1.0f);
  }
  // prefetch row t+2 into buf (distance-2; clamped redundant loads at tail)
  {
    int tp = t + 2;
    if (tp > TT - 1) tp = TT - 1;
    const float* src = base + (size_t)tp * SSZ;
    *(float4*)&buf[0]  = *(const float4*)(src + 0);
    *(float4*)&buf[4]  = *(const float4*)(src + 4);
    *(float4*)&buf[8]  = *(const float4*)(src + 8);
    *(float4*)&buf[12] = *(const float4*)(src + 12);
  }
  // lane-local inclusive products
  float l[16];
  l[0] = f[0];
#pragma unroll
  for (int i = 1; i < 16; ++i) l[i] = l[i - 1] * f[i];
  // wave prefix product of lane totals
  float wincl = wscan_mul(l[15]);
  float wexcl = wave_shr1(wincl, 1.0f);
  // y = prev / clamp(excl_cumprod, EPS, 1); lane-local inclusive sums
  float s[16];
  {
    float cpc = fmaxf(wexcl, EPSF);
    s[0] = prev[0] * __builtin_amdgcn_rcpf(cpc);
  }
#pragma unroll
  for (int i = 1; i < 16; ++i) {
    float cpx = wexcl * l[i - 1];
    float cpc = fmaxf(cpx, EPSF);
    s[i] = s[i - 1] + prev[i] * __builtin_amdgcn_rcpf(cpc);
  }
  float aincl = wscan_add(s[15]);
  float aexcl = wave_shr1(aincl, 0.0f);
  // alpha = clip(p * excl_cumprod * cumsum, 0, 1)
  float alpha[16];
#pragma unroll
  for (int i = 0; i < 16; ++i) {
    float cpx = (i == 0) ? wexcl : wexcl * l[i - 1];
    float C = aexcl + s[i];
    float p = 1.0f - f[i];
    float av = p * cpx * C;
    av = fminf(fmaxf(av, 0.0f), 1.0f);
    alpha[i] = av;
    prev[i] = av;  // carry PRE-residual alpha
  }
  // residual mass onto last source token (store-only)
  float la = 0.0f;
#pragma unroll
  for (int i = 0; i < 16; ++i) la += alpha[i];
  float totincl = wscan_add(la);  // lane 63 holds full row sum
  if (lane == 63) {
    float rest = totincl - alpha[15];
    alpha[15] = 1.0f - fminf(fmaxf(rest, 0.0f), 1.0f);
  }
  float* dst = base + (size_t)t * SSZ;
  *(float4*)(dst + 0)  = make_float4(alpha[0], alpha[1], alpha[2], alpha[3]);
  *(float4*)(dst + 4)  = make_float4(alpha[4], alpha[5], alpha[6], alpha[7]);
  *(float4*)(dst + 8)  = make_float4(alpha[8], alpha[9], alpha[10], alpha[11]);
  *(float4*)(dst + 12) = make_float4(alpha[12], alpha[13], alpha[14], alpha[15]);
}

__global__ __launch_bounds__(64) void k_scan(float* __restrict__ A) {
  const int b = blockIdx.x;
  const int lane = threadIdx.x;
  float* base = A + (size_t)b * TT * SSZ + lane * 16;

  float prev[16];
#pragma unroll
  for (int i = 0; i < 16; ++i) prev[i] = 0.0f;
  if (lane == 0) prev[0] = 1.0f;

  float bufA[16], bufB[16];
  {
    const float* s0 = base;
    const float* s1 = base + SSZ;
    *(float4*)&bufA[0]  = *(const float4*)(s0 + 0);
    *(float4*)&bufA[4]  = *(const float4*)(s0 + 4);
    *(float4*)&bufA[8]  = *(const float4*)(s0 + 8);
    *(float4*)&bufA[12] = *(const float4*)(s0 + 12);
    *(float4*)&bufB[0]  = *(const float4*)(s1 + 0);
    *(float4*)&bufB[4]  = *(const float4*)(s1 + 4);
    *(float4*)&bufB[8]  = *(const float4*)(s1 + 8);
    *(float4*)&bufB[12] = *(const float4*)(s1 + 12);
  }

  for (int t = 0; t < TT; t += 2) {
    scan_step(prev, bufA, base, t, lane);
    scan_step(prev, bufB, base, t + 1, lane);
  }
}

// ---------------- K3: X[t,bz,h*64+d] = sum_s alpha[bh,t,s] * V[bh,s,d] ----------------
__global__ __launch_bounds__(256) void k_av(const float* __restrict__ Al,
                                            const float* __restrict__ V) {
  __shared__ float As[64][132];  // [k(s)][m(t)] transposed
  __shared__ float Bs[64][64];   // [k(s)][n(d)] natural
  const int tid = threadIdx.x;
  const int bh = blockIdx.x >> 3;
  const int m0 = (blockIdx.x & 7) << 7;
  const int bz = bh >> 4, hh = bh & 15;
  const float* ab = Al + (size_t)bh * TT * SSZ;
  const float* vb = V + (size_t)bh * SSZ * DD;
  const int tx = tid & 15, ty = tid >> 4;

  float acc[8][4];
#pragma unroll
  for (int i = 0; i < 8; ++i)
#pragma unroll
    for (int j = 0; j < 4; ++j) acc[i][j] = 0.0f;

  for (int s0 = 0; s0 < SSZ; s0 += 64) {
    {
      const int kc = (tid & 15) << 2;
      const int rr = (tid >> 4) << 2;
#pragma unroll
      for (int pass = 0; pass < 2; ++pass) {
        const int r = rr + (pass << 6);
        float4 a0 = *(const float4*)(ab + (size_t)(m0 + r + 0) * SSZ + s0 + kc);
        float4 a1 = *(const float4*)(ab + (size_t)(m0 + r + 1) * SSZ + s0 + kc);
        float4 a2 = *(const float4*)(ab + (size_t)(m0 + r + 2) * SSZ + s0 + kc);
        float4 a3 = *(const float4*)(ab + (size_t)(m0 + r + 3) * SSZ + s0 + kc);
        *(float4*)&As[kc + 0][r] = make_float4(a0.x, a1.x, a2.x, a3.x);
        *(float4*)&As[kc + 1][r] = make_float4(a0.y, a1.y, a2.y, a3.y);
        *(float4*)&As[kc + 2][r] = make_float4(a0.z, a1.z, a2.z, a3.z);
        *(float4*)&As[kc + 3][r] = make_float4(a0.w, a1.w, a2.w, a3.w);
      }
#pragma unroll
      for (int pass = 0; pass < 4; ++pass) {
        const int vr = (tid >> 4) + (pass << 4);
        const int vc = (tid & 15) << 2;
        *(float4*)&Bs[vr][vc] = *(const float4*)(vb + (size_t)(s0 + vr) * DD + vc);
      }
    }
    __syncthreads();
#pragma unroll 8
    for (int k = 0; k < 64; ++k) {
      float4 a0 = *(const float4*)&As[k][ty << 3];
      float4 a1 = *(const float4*)&As[k][(ty << 3) + 4];
      float4 b0 = *(const float4*)&Bs[k][tx << 2];
      float av[8] = {a0.x, a0.y, a0.z, a0.w, a1.x, a1.y, a1.z, a1.w};
      float bv[4] = {b0.x, b0.y, b0.z, b0.w};
#pragma unroll
      for (int i = 0; i < 8; ++i)
#pragma unroll
        for (int j = 0; j < 4; ++j) acc[i][j] = fmaf(av[i], bv[j], acc[i][j]);
    }
    __syncthreads();
  }
#pragma unroll
  for (int i = 0; i < 8; ++i) {
    const int t = m0 + (ty << 3) + i;
    float* dst = g_X + ((size_t)t * BSZN + bz) * EEN + hh * DD + (tx << 2);
    *(float4*)dst = make_float4(acc[i][0], acc[i][1], acc[i][2], acc[i][3]);
  }
}

// ---------------- K4: Out = X @ W^T + b ----------------
__global__ __launch_bounds__(256) void k_out(const float* __restrict__ W,
                                             const float* __restrict__ Bb,
                                             float* __restrict__ Out) {
  __shared__ float As[32][132];
  __shared__ float Bs[32][132];
  const int tid = threadIdx.x;
  const int m0 = (blockIdx.x >> 3) << 7;
  const int n0 = (blockIdx.x & 7) << 7;
  const int tx = tid & 15, ty = tid >> 4;
  const int kc = (tid & 7) << 2;
  const int r = (tid >> 3) << 2;

  float acc[8][8];
#pragma unroll
  for (int i = 0; i < 8; ++i)
#pragma unroll
    for (int j = 0; j < 8; ++j) acc[i][j] = 0.0f;

  for (int k0 = 0; k0 < EEN; k0 += 32) {
    {
      float4 x0 = *(const float4*)(g_X + (size_t)(m0 + r + 0) * EEN + k0 + kc);
      float4 x1 = *(const float4*)(g_X + (size_t)(m0 + r + 1) * EEN + k0 + kc);
      float4 x2 = *(const float4*)(g_X + (size_t)(m0 + r + 2) * EEN + k0 + kc);
      float4 x3 = *(const float4*)(g_X + (size_t)(m0 + r + 3) * EEN + k0 + kc);
      *(float4*)&As[kc + 0][r] = make_float4(x0.x, x1.x, x2.x, x3.x);
      *(float4*)&As[kc + 1][r] = make_float4(x0.y, x1.y, x2.y, x3.y);
      *(float4*)&As[kc + 2][r] = make_float4(x0.z, x1.z, x2.z, x3.z);
      *(float4*)&As[kc + 3][r] = make_float4(x0.w, x1.w, x2.w, x3.w);
      float4 w0 = *(const float4*)(W + (size_t)(n0 + r + 0) * EEN + k0 + kc);
      float4 w1 = *(const float4*)(W + (size_t)(n0 + r + 1) * EEN + k0 + kc);
      float4 w2 = *(const float4*)(W + (size_t)(n0 + r + 2) * EEN + k0 + kc);
      float4 w3 = *(const float4*)(W + (size_t)(n0 + r + 3) * EEN + k0 + kc);
      *(float4*)&Bs[kc + 0][r] = make_float4(w0.x, w1.x, w2.x, w3.x);
      *(float4*)&Bs[kc + 1][r] = make_float4(w0.y, w1.y, w2.y, w3.y);
      *(float4*)&Bs[kc + 2][r] = make_float4(w0.z, w1.z, w2.z, w3.z);
      *(float4*)&Bs[kc + 3][r] = make_float4(w0.w, w1.w, w2.w, w3.w);
    }
    __syncthreads();
#pragma unroll 8
    for (int k = 0; k < 32; ++k) {
      float4 a0 = *(const float4*)&As[k][ty << 3];
      float4 a1 = *(const float4*)&As[k][(ty << 3) + 4];
      float4 b0 = *(const float4*)&Bs[k][tx << 3];
      float4 b1 = *(const float4*)&Bs[k][(tx << 3) + 4];
      float av[8] = {a0.x, a0.y, a0.z, a0.w, a1.x, a1.y, a1.z, a1.w};
      float bv[8] = {b0.x, b0.y, b0.z, b0.w, b1.x, b1.y, b1.z, b1.w};
#pragma unroll
      for (int i = 0; i < 8; ++i)
#pragma unroll
        for (int j = 0; j < 8; ++j) acc[i][j] = fmaf(av[i], bv[j], acc[i][j]);
    }
    __syncthreads();
  }

  float4 bb0 = *(const float4*)(Bb + n0 + (tx << 3));
  float4 bb1 = *(const float4*)(Bb + n0 + (tx << 3) + 4);
  float bv[8] = {bb0.x, bb0.y, bb0.z, bb0.w, bb1.x, bb1.y, bb1.z, bb1.w};
#pragma unroll
  for (int i = 0; i < 8; ++i) {
    float o[8];
#pragma unroll
    for (int j = 0; j < 8; ++j) o[j] = acc[i][j] + bv[j];
    float* dst = Out + (size_t)(m0 + (ty << 3) + i) * EEN + n0 + (tx << 3);
    *(float4*)dst = make_float4(o[0], o[1], o[2], o[3]);
    *(float4*)(dst + 4) = make_float4(o[4], o[5], o[6], o[7]);
  }
}

extern "C" void kernel_launch(void* const* d_in, const int* in_sizes, int n_in,
                              void* d_out, int out_size, void* d_ws, size_t ws_size,
                              hipStream_t stream) {
  const float* Q  = (const float*)d_in[0];
  const float* K  = (const float*)d_in[1];
  const float* V  = (const float*)d_in[2];
  const float* W  = (const float*)d_in[3];
  const float* Bb = (const float*)d_in[4];
  const float* eb = (const float*)d_in[5];
  float* Out = (float*)d_out;
  float* Alpha = Out + (size_t)TT * BSZN * EEN;  // output #1 region, also staging for p_choose

  k_energy<<<dim3(BHN * 64), dim3(256), 0, stream>>>(Q, K, eb, Alpha);
  k_scan<<<dim3(BHN), dim3(64), 0, stream>>>(Alpha);
  k_av<<<dim3(BHN * 8), dim3(256), 0, stream>>>(Alpha, V);
  k_out<<<dim3(256), dim3(256), 0, stream>>>(W, Bb, Out);
}

// Round 2
// 948.354 us; speedup vs baseline: 1.1224x; 1.1224x over previous
//
#include <hip/hip_runtime.h>

#define TT 1024
#define SSZ 1024
#define DD 64
#define BHN 64
#define BSZN 4
#define EEN 1024
#define EPSF 1e-6f

// scratch for the gathered attention matrix [T, BSZ, E] = 16 MB (static to avoid ws_size assumptions)
__device__ float g_X[(size_t)TT * BSZN * EEN];

// ---------------- DPP helpers (canonical gfx9 64-lane scan stages) ----------------
template<int CTRL, int RM>
__device__ __forceinline__ float f_dpp(float x, float ident) {
  return __builtin_bit_cast(float,
      __builtin_amdgcn_update_dpp(__builtin_bit_cast(int, ident),
                                  __builtin_bit_cast(int, x),
                                  CTRL, RM, 0xF, false));
}

__device__ __forceinline__ float wscan_add(float x) {
  x += f_dpp<0x111, 0xF>(x, 0.0f);
  x += f_dpp<0x112, 0xF>(x, 0.0f);
  x += f_dpp<0x114, 0xF>(x, 0.0f);
  x += f_dpp<0x118, 0xF>(x, 0.0f);
  x += f_dpp<0x142, 0xA>(x, 0.0f);
  x += f_dpp<0x143, 0xC>(x, 0.0f);
  return x;
}

__device__ __forceinline__ float wave_shr1(float x, float ident) {
  return f_dpp<0x138, 0xF>(x, ident);  // wave_shr:1 (lane0 -> ident)
}

// ---------------- K1: p_choose = sigmoid(Q K^T + bias) -> alpha region ----------------
__global__ __launch_bounds__(256) void k_energy(const float* __restrict__ Q,
                                                const float* __restrict__ Kp,
                                                const float* __restrict__ eb,
                                                float* __restrict__ P) {
  __shared__ float As[64][132];  // [k][m], transposed
  __shared__ float Bs[64][132];  // [k][n], transposed
  const int tid = threadIdx.x;
  const int b = blockIdx.x >> 6;
  const int tile = blockIdx.x & 63;
  const int m0 = (tile >> 3) << 7;
  const int n0 = (tile & 7) << 7;

  {
    const int kc = (tid & 15) << 2;
    const int rr = (tid >> 4) << 2;
    const float* qb = Q + (size_t)b * TT * DD;
    const float* kb = Kp + (size_t)b * SSZ * DD;
#pragma unroll
    for (int pass = 0; pass < 2; ++pass) {
      const int r = rr + (pass << 6);
      float4 a0 = *(const float4*)(qb + (size_t)(m0 + r + 0) * DD + kc);
      float4 a1 = *(const float4*)(qb + (size_t)(m0 + r + 1) * DD + kc);
      float4 a2 = *(const float4*)(qb + (size_t)(m0 + r + 2) * DD + kc);
      float4 a3 = *(const float4*)(qb + (size_t)(m0 + r + 3) * DD + kc);
      *(float4*)&As[kc + 0][r] = make_float4(a0.x, a1.x, a2.x, a3.x);
      *(float4*)&As[kc + 1][r] = make_float4(a0.y, a1.y, a2.y, a3.y);
      *(float4*)&As[kc + 2][r] = make_float4(a0.z, a1.z, a2.z, a3.z);
      *(float4*)&As[kc + 3][r] = make_float4(a0.w, a1.w, a2.w, a3.w);
      float4 b0 = *(const float4*)(kb + (size_t)(n0 + r + 0) * DD + kc);
      float4 b1 = *(const float4*)(kb + (size_t)(n0 + r + 1) * DD + kc);
      float4 b2 = *(const float4*)(kb + (size_t)(n0 + r + 2) * DD + kc);
      float4 b3 = *(const float4*)(kb + (size_t)(n0 + r + 3) * DD + kc);
      *(float4*)&Bs[kc + 0][r] = make_float4(b0.x, b1.x, b2.x, b3.x);
      *(float4*)&Bs[kc + 1][r] = make_float4(b0.y, b1.y, b2.y, b3.y);
      *(float4*)&Bs[kc + 2][r] = make_float4(b0.z, b1.z, b2.z, b3.z);
      *(float4*)&Bs[kc + 3][r] = make_float4(b0.w, b1.w, b2.w, b3.w);
    }
  }
  __syncthreads();

  const int tx = tid & 15, ty = tid >> 4;
  float acc[8][8];
#pragma unroll
  for (int i = 0; i < 8; ++i)
#pragma unroll
    for (int j = 0; j < 8; ++j) acc[i][j] = 0.0f;

#pragma unroll 8
  for (int k = 0; k < 64; ++k) {
    float4 a0 = *(const float4*)&As[k][ty << 3];
    float4 a1 = *(const float4*)&As[k][(ty << 3) + 4];
    float4 b0 = *(const float4*)&Bs[k][tx << 3];
    float4 b1 = *(const float4*)&Bs[k][(tx << 3) + 4];
    float av[8] = {a0.x, a0.y, a0.z, a0.w, a1.x, a1.y, a1.z, a1.w};
    float bv[8] = {b0.x, b0.y, b0.z, b0.w, b1.x, b1.y, b1.z, b1.w};
#pragma unroll
    for (int i = 0; i < 8; ++i)
#pragma unroll
      for (int j = 0; j < 8; ++j) acc[i][j] = fmaf(av[i], bv[j], acc[i][j]);
  }

  const float bias = eb[0];
#pragma unroll
  for (int i = 0; i < 8; ++i) {
    const size_t row = (size_t)b * TT + m0 + (ty << 3) + i;
    float o[8];
#pragma unroll
    for (int j = 0; j < 8; ++j) {
      float x = acc[i][j] + bias;
      o[j] = __builtin_amdgcn_rcpf(1.0f + __expf(-x));  // sigmoid
    }
    float* dst = P + row * SSZ + n0 + (tx << 3);
    *(float4*)dst = make_float4(o[0], o[1], o[2], o[3]);
    *(float4*)(dst + 4) = make_float4(o[4], o[5], o[6], o[7]);
  }
}

// ---------------- K2: expected-alignment scan, division-free D-recurrence ----------------
// D_i = cpx_i * C_i obeys: D_i = f_{i-1} * D_{i-1} + prev_i * min(cpx_i*1e6, 1)
// alpha_i = min(p_i * D_i, 1) = min(D_i - f_i*D_i, 1)
// One fused (A,B) linear-recurrence DPP wave scan; A-stage chain is prev-independent.
__global__ __launch_bounds__(64, 1) void k_scan(float* __restrict__ A) {
  const int b = blockIdx.x;
  const int lane = threadIdx.x;
  float* base = A + (size_t)b * TT * SSZ + lane * 16;

  float prev[16];
#pragma unroll
  for (int i = 0; i < 16; ++i) prev[i] = 0.0f;
  if (lane == 0) prev[0] = 1.0f;

  // 4 rotating prefetch buffers, distance 4
  float buf[4][16];
#pragma unroll
  for (int u = 0; u < 4; ++u) {
    const float* src = base + (size_t)u * SSZ;
    *(float4*)&buf[u][0]  = *(const float4*)(src + 0);
    *(float4*)&buf[u][4]  = *(const float4*)(src + 4);
    *(float4*)&buf[u][8]  = *(const float4*)(src + 8);
    *(float4*)&buf[u][12] = *(const float4*)(src + 12);
  }

  for (int t0 = 0; t0 < TT; t0 += 4) {
#pragma unroll
    for (int u = 0; u < 4; ++u) {
      const int t = t0 + u;
      // ---- extract f = 1-p from buf[u], then immediately re-prefetch into it ----
      float f[16];
#pragma unroll
      for (int i = 0; i < 16; ++i) f[i] = 1.0f - buf[u][i];
      {
        int tp = t + 4; if (tp > TT - 1) tp = TT - 1;
        const float* src = base + (size_t)tp * SSZ;
        *(float4*)&buf[u][0]  = *(const float4*)(src + 0);
        *(float4*)&buf[u][4]  = *(const float4*)(src + 4);
        *(float4*)&buf[u][8]  = *(const float4*)(src + 8);
        *(float4*)&buf[u][12] = *(const float4*)(src + 12);
      }
      // ---- p-side (prev-independent) ----
      float fpl = wave_shr1(f[15], 1.0f);            // f of previous lane's last elem
      float l[16];
      l[0] = f[0];
#pragma unroll
      for (int i = 1; i < 16; ++i) l[i] = l[i - 1] * f[i];
      // lane-local products of a_k = f[k-1]
      float al[8];  // al[i] = prod a_{0..i} = fpl * l[i-1]
      al[0] = fpl;
#pragma unroll
      for (int i = 1; i < 8; ++i) al[i] = al[i - 1] * f[i - 1];
      float ah[8];  // ah[j] = prod a_{8..8+j} = prod f[7..7+j]
      ah[0] = f[7];
#pragma unroll
      for (int j = 1; j < 8; ++j) ah[j] = ah[j - 1] * f[7 + j];
      float Atot = al[7] * ah[7];
      // A-stage chain (prev-independent) — keep pre-stage values for the B scan
      float A0 = Atot;
      float A1 = A0 * f_dpp<0x111, 0xF>(A0, 1.0f);
      float A2 = A1 * f_dpp<0x112, 0xF>(A1, 1.0f);
      float A3 = A2 * f_dpp<0x114, 0xF>(A2, 1.0f);
      float A4 = A3 * f_dpp<0x118, 0xF>(A3, 1.0f);
      float A5 = A4 * f_dpp<0x142, 0xA>(A4, 1.0f);
      float A6 = A5 * f_dpp<0x143, 0xC>(A5, 1.0f);
      float Aexcl = wave_shr1(A6, 1.0f);
      float wx6 = Aexcl * fpl * 1e6f;                // wexcl * 1e6
      // ---- carried: b_i = prev_i * min(cpx_i*1e6, 1) = min(cpx6_i*prev_i, prev_i) ----
      float bb[16];
      bb[0] = fminf(wx6 * prev[0], prev[0]);
#pragma unroll
      for (int i = 1; i < 16; ++i) {
        float c6 = wx6 * l[i - 1];
        bb[i] = fminf(c6 * prev[i], prev[i]);
      }
      // two 8-deep local chains (D_in = 0)
      float Blo[8];
      Blo[0] = bb[0];
#pragma unroll
      for (int i = 1; i < 8; ++i) Blo[i] = fmaf(f[i - 1], Blo[i - 1], bb[i]);
      float Bhi[8];
      Bhi[0] = bb[8];
#pragma unroll
      for (int j = 1; j < 8; ++j) Bhi[j] = fmaf(f[7 + j], Bhi[j - 1], bb[8 + j]);
      float Btot = fmaf(ah[7], Blo[7], Bhi[7]);
      // B wave scan (carried path: 6 x (dpp + fma)); multipliers are pre-stage A values
      float B = Btot;
      B = fmaf(A0, f_dpp<0x111, 0xF>(B, 0.0f), B);
      B = fmaf(A1, f_dpp<0x112, 0xF>(B, 0.0f), B);
      B = fmaf(A2, f_dpp<0x114, 0xF>(B, 0.0f), B);
      B = fmaf(A3, f_dpp<0x118, 0xF>(B, 0.0f), B);
      B = fmaf(A4, f_dpp<0x142, 0xA>(B, 0.0f), B);
      B = fmaf(A5, f_dpp<0x143, 0xC>(B, 0.0f), B);
      float carry = wave_shr1(B, 0.0f);
      // ---- D and alpha ----
      float D[16];
#pragma unroll
      for (int i = 0; i < 8; ++i) D[i] = fmaf(al[i], carry, Blo[i]);
#pragma unroll
      for (int j = 0; j < 8; ++j) D[8 + j] = fmaf(ah[j], D[7], Bhi[j]);
      float alpha[16];
#pragma unroll
      for (int i = 0; i < 16; ++i) {
        float av = fmaf(-f[i], D[i], D[i]);          // p_i * D_i
        av = fminf(av, 1.0f);
        alpha[i] = av;
        prev[i] = av;                                 // carry PRE-residual alpha
      }
      // ---- residual mass on s = S-1 (store-only) ----
      float la = 0.0f;
#pragma unroll
      for (int i = 0; i < 16; ++i) la += alpha[i];
      float totincl = wscan_add(la);                  // lane 63 holds full row sum
      if (lane == 63) {
        float rest = totincl - alpha[15];
        alpha[15] = 1.0f - fminf(fmaxf(rest, 0.0f), 1.0f);
      }
      float* dst = base + (size_t)t * SSZ;
      *(float4*)(dst + 0)  = make_float4(alpha[0], alpha[1], alpha[2], alpha[3]);
      *(float4*)(dst + 4)  = make_float4(alpha[4], alpha[5], alpha[6], alpha[7]);
      *(float4*)(dst + 8)  = make_float4(alpha[8], alpha[9], alpha[10], alpha[11]);
      *(float4*)(dst + 12) = make_float4(alpha[12], alpha[13], alpha[14], alpha[15]);
    }
  }
}

// ---------------- K3: X[t,bz,h*64+d] = sum_s alpha[bh,t,s] * V[bh,s,d] ----------------
__global__ __launch_bounds__(256) void k_av(const float* __restrict__ Al,
                                            const float* __restrict__ V) {
  __shared__ float As[64][132];  // [k(s)][m(t)] transposed
  __shared__ float Bs[64][64];   // [k(s)][n(d)] natural
  const int tid = threadIdx.x;
  const int bh = blockIdx.x >> 3;
  const int m0 = (blockIdx.x & 7) << 7;
  const int bz = bh >> 4, hh = bh & 15;
  const float* ab = Al + (size_t)bh * TT * SSZ;
  const float* vb = V + (size_t)bh * SSZ * DD;
  const int tx = tid & 15, ty = tid >> 4;

  float acc[8][4];
#pragma unroll
  for (int i = 0; i < 8; ++i)
#pragma unroll
    for (int j = 0; j < 4; ++j) acc[i][j] = 0.0f;

  for (int s0 = 0; s0 < SSZ; s0 += 64) {
    {
      const int kc = (tid & 15) << 2;
      const int rr = (tid >> 4) << 2;
#pragma unroll
      for (int pass = 0; pass < 2; ++pass) {
        const int r = rr + (pass << 6);
        float4 a0 = *(const float4*)(ab + (size_t)(m0 + r + 0) * SSZ + s0 + kc);
        float4 a1 = *(const float4*)(ab + (size_t)(m0 + r + 1) * SSZ + s0 + kc);
        float4 a2 = *(const float4*)(ab + (size_t)(m0 + r + 2) * SSZ + s0 + kc);
        float4 a3 = *(const float4*)(ab + (size_t)(m0 + r + 3) * SSZ + s0 + kc);
        *(float4*)&As[kc + 0][r] = make_float4(a0.x, a1.x, a2.x, a3.x);
        *(float4*)&As[kc + 1][r] = make_float4(a0.y, a1.y, a2.y, a3.y);
        *(float4*)&As[kc + 2][r] = make_float4(a0.z, a1.z, a2.z, a3.z);
        *(float4*)&As[kc + 3][r] = make_float4(a0.w, a1.w, a2.w, a3.w);
      }
#pragma unroll
      for (int pass = 0; pass < 4; ++pass) {
        const int vr = (tid >> 4) + (pass << 4);
        const int vc = (tid & 15) << 2;
        *(float4*)&Bs[vr][vc] = *(const float4*)(vb + (size_t)(s0 + vr) * DD + vc);
      }
    }
    __syncthreads();
#pragma unroll 8
    for (int k = 0; k < 64; ++k) {
      float4 a0 = *(const float4*)&As[k][ty << 3];
      float4 a1 = *(const float4*)&As[k][(ty << 3) + 4];
      float4 b0 = *(const float4*)&Bs[k][tx << 2];
      float av[8] = {a0.x, a0.y, a0.z, a0.w, a1.x, a1.y, a1.z, a1.w};
      float bv[4] = {b0.x, b0.y, b0.z, b0.w};
#pragma unroll
      for (int i = 0; i < 8; ++i)
#pragma unroll
        for (int j = 0; j < 4; ++j) acc[i][j] = fmaf(av[i], bv[j], acc[i][j]);
    }
    __syncthreads();
  }
#pragma unroll
  for (int i = 0; i < 8; ++i) {
    const int t = m0 + (ty << 3) + i;
    float* dst = g_X + ((size_t)t * BSZN + bz) * EEN + hh * DD + (tx << 2);
    *(float4*)dst = make_float4(acc[i][0], acc[i][1], acc[i][2], acc[i][3]);
  }
}

// ---------------- K4: Out = X @ W^T + b ----------------
__global__ __launch_bounds__(256) void k_out(const float* __restrict__ W,
                                             const float* __restrict__ Bb,
                                             float* __restrict__ Out) {
  __shared__ float As[32][132];
  __shared__ float Bs[32][132];
  const int tid = threadIdx.x;
  const int m0 = (blockIdx.x >> 3) << 7;
  const int n0 = (blockIdx.x & 7) << 7;
  const int tx = tid & 15, ty = tid >> 4;
  const int kc = (tid & 7) << 2;
  const int r = (tid >> 3) << 2;

  float acc[8][8];
#pragma unroll
  for (int i = 0; i < 8; ++i)
#pragma unroll
    for (int j = 0; j < 8; ++j) acc[i][j] = 0.0f;

  for (int k0 = 0; k0 < EEN; k0 += 32) {
    {
      float4 x0 = *(const float4*)(g_X + (size_t)(m0 + r + 0) * EEN + k0 + kc);
      float4 x1 = *(const float4*)(g_X + (size_t)(m0 + r + 1) * EEN + k0 + kc);
      float4 x2 = *(const float4*)(g_X + (size_t)(m0 + r + 2) * EEN + k0 + kc);
      float4 x3 = *(const float4*)(g_X + (size_t)(m0 + r + 3) * EEN + k0 + kc);
      *(float4*)&As[kc + 0][r] = make_float4(x0.x, x1.x, x2.x, x3.x);
      *(float4*)&As[kc + 1][r] = make_float4(x0.y, x1.y, x2.y, x3.y);
      *(float4*)&As[kc + 2][r] = make_float4(x0.z, x1.z, x2.z, x3.z);
      *(float4*)&As[kc + 3][r] = make_float4(x0.w, x1.w, x2.w, x3.w);
      float4 w0 = *(const float4*)(W + (size_t)(n0 + r + 0) * EEN + k0 + kc);
      float4 w1 = *(const float4*)(W + (size_t)(n0 + r + 1) * EEN + k0 + kc);
      float4 w2 = *(const float4*)(W + (size_t)(n0 + r + 2) * EEN + k0 + kc);
      float4 w3 = *(const float4*)(W + (size_t)(n0 + r + 3) * EEN + k0 + kc);
      *(float4*)&Bs[kc + 0][r] = make_float4(w0.x, w1.x, w2.x, w3.x);
      *(float4*)&Bs[kc + 1][r] = make_float4(w0.y, w1.y, w2.y, w3.y);
      *(float4*)&Bs[kc + 2][r] = make_float4(w0.z, w1.z, w2.z, w3.z);
      *(float4*)&Bs[kc + 3][r] = make_float4(w0.w, w1.w, w2.w, w3.w);
    }
    __syncthreads();
#pragma unroll 8
    for (int k = 0; k < 32; ++k) {
      float4 a0 = *(const float4*)&As[k][ty << 3];
      float4 a1 = *(const float4*)&As[k][(ty << 3) + 4];
      float4 b0 = *(const float4*)&Bs[k][tx << 3];
      float4 b1 = *(const float4*)&Bs[k][(tx << 3) + 4];
      float av[8] = {a0.x, a0.y, a0.z, a0.w, a1.x, a1.y, a1.z, a1.w};
      float bv[8] = {b0.x, b0.y, b0.z, b0.w, b1.x, b1.y, b1.z, b1.w};
#pragma unroll
      for (int i = 0; i < 8; ++i)
#pragma unroll
        for (int j = 0; j < 8; ++j) acc[i][j] = fmaf(av[i], bv[j], acc[i][j]);
    }
    __syncthreads();
  }

  float4 bb0 = *(const float4*)(Bb + n0 + (tx << 3));
  float4 bb1 = *(const float4*)(Bb + n0 + (tx << 3) + 4);
  float bv[8] = {bb0.x, bb0.y, bb0.z, bb0.w, bb1.x, bb1.y, bb1.z, bb1.w};
#pragma unroll
  for (int i = 0; i < 8; ++i) {
    float o[8];
#pragma unroll
    for (int j = 0; j < 8; ++j) o[j] = acc[i][j] + bv[j];
    float* dst = Out + (size_t)(m0 + (ty << 3) + i) * EEN + n0 + (tx << 3);
    *(float4*)dst = make_float4(o[0], o[1], o[2], o[3]);
    *(float4*)(dst + 4) = make_float4(o[4], o[5], o[6], o[7]);
  }
}

extern "C" void kernel_launch(void* const* d_in, const int* in_sizes, int n_in,
                              void* d_out, int out_size, void* d_ws, size_t ws_size,
                              hipStream_t stream) {
  const float* Q  = (const float*)d_in[0];
  const float* K  = (const float*)d_in[1];
  const float* V  = (const float*)d_in[2];
  const float* W  = (const float*)d_in[3];
  const float* Bb = (const float*)d_in[4];
  const float* eb = (const float*)d_in[5];
  float* Out = (float*)d_out;
  float* Alpha = Out + (size_t)TT * BSZN * EEN;  // output #1 region, also staging for p_choose

  k_energy<<<dim3(BHN * 64), dim3(256), 0, stream>>>(Q, K, eb, Alpha);
  k_scan<<<dim3(BHN), dim3(64), 0, stream>>>(Alpha);
  k_av<<<dim3(BHN * 8), dim3(256), 0, stream>>>(Alpha, V);
  k_out<<<dim3(256), dim3(256), 0, stream>>>(W, Bb, Out);
}